// Round 3
// baseline (338.596 us; speedup 1.0000x reference)
//
#include <hip/hip_runtime.h>

// ---------------------------------------------------------------------------
// HopfieldLayer via 3x MX-fp8 MFMA GEMMs (mfma_scale_f32_16x16x128_f8f6f4,
// uniform scales = 1.0). Softmax folded: GEMM2 stores F = 32*(exp(beta*l)-1)
// in fp8 + fp32 row sums; GEMM3 computes
// out = (colsum + F@xi/32) / (8192 + rowsum/32) with exact fp32 colsum.
// fp8 outputs are packed 4B/lane -> K-permuted layout (sigma within
// 128-chunks) matched by xi8/xit8 prep; dot products are perm-invariant.
// R3: fragment loads via shufflevector(int4v,int4v) to keep ds_read_b128
// (R2 element-wise assembly scalarized to ds_read_b32 -> 8-way conflicts,
// 256 extra LDS cyc/block-iter). GEMM2 uses 256x128 block (wave 128x64)
// to lift FLOP per LDS byte from 64 to 85 -> MFMA-bound.
// ---------------------------------------------------------------------------

typedef __attribute__((ext_vector_type(8))) int int8v;   // 32 fp8 bytes
typedef __attribute__((ext_vector_type(4))) int int4v;   // 16 bytes
typedef __attribute__((ext_vector_type(4))) float f32x4; // MFMA C/D 16x16

#define NDIM 1024
#define NPAT 8192
#define NROW 8192

__device__ __forceinline__ unsigned f8pack4(float a, float b, float c, float d) {
  int w = __builtin_amdgcn_cvt_pk_fp8_f32(a, b, 0, false);
  w = __builtin_amdgcn_cvt_pk_fp8_f32(c, d, w, true);
  return (unsigned)w;
}
__device__ __forceinline__ unsigned char f8b(float v) {
  return (unsigned char)(__builtin_amdgcn_cvt_pk_fp8_f32(v, v, 0, false) & 0xff);
}
// sigma: original col c (0..127) -> packed byte index
__device__ __forceinline__ int sig(int c) {
  return (c & 64) | ((c & 15) << 2) | ((c >> 4) & 3);
}

__device__ __forceinline__ void gload_lds16(const void* g, void* l) {
  __builtin_amdgcn_global_load_lds(
      (const __attribute__((address_space(1))) unsigned char*)g,
      (__attribute__((address_space(3))) unsigned char*)l,
      16, 0, 0);
}

// --------------------------- prep kernels ----------------------------------

__global__ void cast_f8(const float* __restrict__ in,
                        unsigned* __restrict__ out, float scale, int n4) {
  int i = blockIdx.x * blockDim.x + threadIdx.x;
  if (i < n4) {
    float4 v = ((const float4*)in)[i];
    out[i] = f8pack4(v.x * scale, v.y * scale, v.z * scale, v.w * scale);
  }
}

// xi f32 [8192,1024] -> xi8 fp8(32*xi) [8192,1024] (sigma on d within 128),
// xit8 fp8(32*xi) [1024,8192] (sigma on p within 128), colsum[1024] fp32.
__global__ void xi_prep8(const float* __restrict__ xi,
                         unsigned char* __restrict__ xi8,
                         unsigned char* __restrict__ xit8,
                         float* __restrict__ colsum) {
  __shared__ float t[32][33];
  __shared__ float cs[8][32];
  int tx = threadIdx.x, ty = threadIdx.y;
  int d0 = blockIdx.x * 32, p0 = blockIdx.y * 32;
  int d = d0 + tx;
  int di = (d & ~127) + sig(d & 127);
  float psum = 0.f;
#pragma unroll
  for (int j = 0; j < 32; j += 8) {
    float v = xi[(long)(p0 + ty + j) * NDIM + d];
    t[ty + j][tx] = v;
    psum += v;
    xi8[(long)(p0 + ty + j) * NDIM + di] = f8b(32.f * v);
  }
  cs[ty][tx] = psum;
  __syncthreads();
  if (ty == 0) {
    float s = 0.f;
#pragma unroll
    for (int k = 0; k < 8; ++k) s += cs[k][tx];
    atomicAdd(&colsum[d0 + tx], s);
  }
  int p = p0 + tx;
  int pi = (p & ~127) + sig(p & 127);
#pragma unroll
  for (int j = 0; j < 32; j += 8)
    xit8[(long)(d0 + ty + j) * NPAT + pi] = f8b(32.f * t[tx][ty + j]);
}

// --------------------------- fp8 GEMM --------------------------------------
// acc[m,n] = sum_k A[m,k]*B[n,k]; A:[M,K] fp8, B:[N,K] fp8, K mult of 128.
// Block tile BM x 128, 256 threads (4 waves 2x2; wave tile BM/2 x 64).
// LDS rows 128B = 8 chunks of 16B, chunk c stored at slot c^(row&7).
// MODE 0: store fp8(acc/32) packed u32   [GEMM1: q]
// MODE 1: F=32*(exp(beta*acc/32)-1); store fp8(F) packed + rowsum atomics
// MODE 2: store f32 (acc/1024 + colsum[col]) / (8192 + rowsum[row]/32)

template <int MODE, int BM>
__launch_bounds__(256, 2)
__global__ void gemm_f8(const unsigned char* __restrict__ A,
                        const unsigned char* __restrict__ B,
                        void* __restrict__ Cv, int N, int K,
                        const float* __restrict__ beta_ptr,
                        const float* __restrict__ rowsum,
                        const float* __restrict__ colsum,
                        float* __restrict__ rowsum_out) {
  constexpr int MT = BM / 32;   // 16-row tiles per wave (wave rows = BM/2)
  constexpr int GA = BM / 32;   // A staging groups per wave
  __shared__ unsigned char smem[BM * 128 + 16384];
  char* Asm = (char*)smem;
  char* Bsm = (char*)smem + BM * 128;

  const int tid = threadIdx.x;
  const int wave = tid >> 6;
  const int lane = tid & 63;
  const int wm = wave >> 1, wn = wave & 1;
  const int quad = lane >> 4, ln = lane & 15;

  const long row0 = (long)blockIdx.y * BM;
  const long col0 = (long)blockIdx.x * 128;

  // staging: each gload covers 8 rows x 128B; lane -> row lane>>3, slot lane&7
  const int r_in = lane >> 3;
  const int csl = lane & 7;
  const int cg = csl ^ r_in;   // slot s of row r holds global chunk s^(r&7)
  const unsigned char* gA[GA];
  const unsigned char* gB[4];
  char* lA[GA];
  char* lB[4];
#pragma unroll
  for (int p = 0; p < GA; ++p) {
    int grp = wave * GA + p;
    gA[p] = A + (row0 + grp * 8 + r_in) * (long)K + cg * 16;
    lA[p] = Asm + grp * 1024;
  }
#pragma unroll
  for (int p = 0; p < 4; ++p) {
    int grp = wave * 4 + p;
    gB[p] = B + (col0 + grp * 8 + r_in) * (long)K + cg * 16;
    lB[p] = Bsm + grp * 1024;
  }

  // fragment addressing: ra&7 == ln&7 (tile strides are mult of 8), so the
  // swizzled slot is mt-independent: 2 byte-offsets + immediate per tile.
  const int s0 = ((2 * quad + 0) ^ (ln & 7)) * 16;
  const int s1 = ((2 * quad + 1) ^ (ln & 7)) * 16;
  const int base_a = (wm * (BM / 2) + ln) * 128;
  const int base_b = (wn * 64 + ln) * 128;

  f32x4 acc[MT][4] = {};

  for (int kt = 0; kt < K; kt += 128) {
#pragma unroll
    for (int p = 0; p < GA; ++p) gload_lds16(gA[p], lA[p]);
#pragma unroll
    for (int p = 0; p < 4; ++p) gload_lds16(gB[p], lB[p]);
#pragma unroll
    for (int p = 0; p < GA; ++p) gA[p] += 128;
#pragma unroll
    for (int p = 0; p < 4; ++p) gB[p] += 128;
    __syncthreads();

    int8v bfv[4];
#pragma unroll
    for (int nt = 0; nt < 4; ++nt) {
      int4v lo = *(const int4v*)(Bsm + base_b + nt * 2048 + s0);
      int4v hi = *(const int4v*)(Bsm + base_b + nt * 2048 + s1);
      bfv[nt] = __builtin_shufflevector(lo, hi, 0, 1, 2, 3, 4, 5, 6, 7);
    }
#pragma unroll
    for (int mg = 0; mg < MT; mg += 4) {
      int8v af[4];
#pragma unroll
      for (int m2 = 0; m2 < 4; ++m2) {
        int4v lo = *(const int4v*)(Asm + base_a + (mg + m2) * 2048 + s0);
        int4v hi = *(const int4v*)(Asm + base_a + (mg + m2) * 2048 + s1);
        af[m2] = __builtin_shufflevector(lo, hi, 0, 1, 2, 3, 4, 5, 6, 7);
      }
#pragma unroll
      for (int m2 = 0; m2 < 4; ++m2)
#pragma unroll
        for (int nt = 0; nt < 4; ++nt)
          acc[mg + m2][nt] = __builtin_amdgcn_mfma_scale_f32_16x16x128_f8f6f4(
              af[m2], bfv[nt], acc[mg + m2][nt], 0, 0, 0, 0x7f7f7f7f, 0,
              0x7f7f7f7f);
    }
    __syncthreads();
  }

  // epilogue. C/D: col = ln (within 16-tile), row = quad*4 + r.
  if (MODE == 0) {
    unsigned* C32 = (unsigned*)Cv;
    const float s = 1.0f / 32.0f;
#pragma unroll
    for (int mt = 0; mt < MT; ++mt)
#pragma unroll
      for (int r = 0; r < 4; ++r) {
        long row = row0 + wm * (BM / 2) + mt * 16 + quad * 4 + r;
        unsigned w = f8pack4(acc[mt][0][r] * s, acc[mt][1][r] * s,
                             acc[mt][2][r] * s, acc[mt][3][r] * s);
        C32[row * (N >> 2) + (col0 >> 2) + wn * 16 + ln] = w;
      }
  } else if (MODE == 1) {
    unsigned* C32 = (unsigned*)Cv;
    const float bs = beta_ptr[0] * (1.0f / 32.0f);
#pragma unroll
    for (int mt = 0; mt < MT; ++mt)
#pragma unroll
      for (int r = 0; r < 4; ++r) {
        long row = row0 + wm * (BM / 2) + mt * 16 + quad * 4 + r;
        float e0 = (__expf(bs * acc[mt][0][r]) - 1.0f) * 32.f;
        float e1 = (__expf(bs * acc[mt][1][r]) - 1.0f) * 32.f;
        float e2 = (__expf(bs * acc[mt][2][r]) - 1.0f) * 32.f;
        float e3 = (__expf(bs * acc[mt][3][r]) - 1.0f) * 32.f;
        C32[row * (N >> 2) + (col0 >> 2) + wn * 16 + ln] =
            f8pack4(e0, e1, e2, e3);
        float s = e0 + e1 + e2 + e3;
        s += __shfl_xor(s, 1, 64);
        s += __shfl_xor(s, 2, 64);
        s += __shfl_xor(s, 4, 64);
        s += __shfl_xor(s, 8, 64);
        if (ln == 0) atomicAdd(&rowsum_out[row], s);
      }
  } else {
    float* C = (float*)Cv;
#pragma unroll
    for (int mt = 0; mt < MT; ++mt)
#pragma unroll
      for (int r = 0; r < 4; ++r) {
        long row = row0 + wm * (BM / 2) + mt * 16 + quad * 4 + r;
        float inv = 1.0f / (8192.0f + rowsum[row] * (1.0f / 32.0f));
#pragma unroll
        for (int nt = 0; nt < 4; ++nt) {
          long col = col0 + wn * 64 + nt * 16 + ln;
          C[row * N + col] =
              (acc[mt][nt][r] * (1.0f / 1024.0f) + colsum[col]) * inv;
        }
      }
  }
}

// --------------------------- launch ----------------------------------------

extern "C" void kernel_launch(void* const* d_in, const int* in_sizes, int n_in,
                              void* d_out, int out_size, void* d_ws,
                              size_t ws_size, hipStream_t stream) {
  const float* x    = (const float*)d_in[0];
  const float* wq   = (const float*)d_in[1];
  const float* xi   = (const float*)d_in[2];
  const float* beta = (const float*)d_in[3];
  float* out = (float*)d_out;

  char* ws = (char*)d_ws;
  const size_t MB = 1024 * 1024;
  unsigned char* x8   = (unsigned char*)(ws);             //  8 MiB
  unsigned char* wq8  = (unsigned char*)(ws + 8 * MB);    //  1 MiB
  unsigned char* q8   = (unsigned char*)(ws + 9 * MB);    //  8 MiB
  unsigned char* xi8  = (unsigned char*)(ws + 17 * MB);   //  8 MiB
  unsigned char* xit8 = (unsigned char*)(ws + 25 * MB);   //  8 MiB
  float*         rs   = (float*)(ws + 33 * MB);           // 32 KiB
  float*         csum = (float*)(ws + 33 * MB + 32768);   //  4 KiB
  unsigned char* E8   = (unsigned char*)(ws + 34 * MB);   // 64 MiB

  hipMemsetAsync(rs, 0, 36864, stream);  // rs + colsum

  cast_f8<<<(NROW * NDIM / 4) / 256, 256, 0, stream>>>(
      x, (unsigned*)x8, 1.0f, NROW * NDIM / 4);
  cast_f8<<<(NDIM * NDIM / 4) / 256, 256, 0, stream>>>(
      wq, (unsigned*)wq8, 32.0f, NDIM * NDIM / 4);
  xi_prep8<<<dim3(NDIM / 32, NPAT / 32), dim3(32, 8), 0, stream>>>(
      xi, xi8, xit8, csum);

  // GEMM1: q = x @ wq^T (acc = 32q), store fp8(q) packed. 512 blocks.
  gemm_f8<0, 128><<<dim3(NDIM / 128, NROW / 128), 256, 0, stream>>>(
      x8, wq8, q8, NDIM, NDIM, nullptr, nullptr, nullptr, nullptr);

  // GEMM2: F = 32*(exp(beta*q.xi)-1), fp8 packed + rowsums. 2048 blocks.
  gemm_f8<1, 256><<<dim3(NPAT / 128, NROW / 256), 256, 0, stream>>>(
      q8, xi8, E8, NPAT, NDIM, beta, nullptr, nullptr, rs);

  // GEMM3: out = (colsum + F@xi/32) / (8192 + rowsum/32). 512 blocks.
  gemm_f8<2, 128><<<dim3(NDIM / 128, NROW / 128), 256, 0, stream>>>(
      E8, xit8, out, NDIM, NPAT, nullptr, rs, csum, nullptr);
}

// Round 4
// 325.765 us; speedup vs baseline: 1.0394x; 1.0394x over previous
//
#include <hip/hip_runtime.h>

// ---------------------------------------------------------------------------
// HopfieldLayer via 3x MX-fp8 MFMA GEMMs (mfma_scale_f32_16x16x128_f8f6f4,
// uniform scales = 1.0). Softmax folded: GEMM2 stores F = 32*(exp(beta*l)-1)
// in fp8 + fp32 row sums; GEMM3 computes
// out = (colsum + F@xi/32) / (8192 + rowsum/32) with exact fp32 colsum.
// fp8 outputs are packed 4B/lane -> K-permuted layout (sigma within
// 128-chunks) matched by xi8/xit8 prep; dot products are perm-invariant.
// R4: LDS swizzle moved to 32B pair-chunk granularity (slot = p^(r&3)) so
// each lane's 32B MFMA operand is ONE aligned int8v load -> 2x ds_read_b128.
// (R2/R3 stitched two 16B pieces -> compiler scalarized to ds_read_b32,
// 1 conflict cyc per read; R1 bf16 with native 16B loads measured 0.)
// ---------------------------------------------------------------------------

typedef __attribute__((ext_vector_type(8))) int int8v;   // 32 fp8 bytes
typedef __attribute__((ext_vector_type(4))) float f32x4; // MFMA C/D 16x16

#define NDIM 1024
#define NPAT 8192
#define NROW 8192

__device__ __forceinline__ unsigned f8pack4(float a, float b, float c, float d) {
  int w = __builtin_amdgcn_cvt_pk_fp8_f32(a, b, 0, false);
  w = __builtin_amdgcn_cvt_pk_fp8_f32(c, d, w, true);
  return (unsigned)w;
}
__device__ __forceinline__ unsigned char f8b(float v) {
  return (unsigned char)(__builtin_amdgcn_cvt_pk_fp8_f32(v, v, 0, false) & 0xff);
}
// sigma: original col c (0..127) -> packed byte index (epilogue pack order)
__device__ __forceinline__ int sig(int c) {
  return (c & 64) | ((c & 15) << 2) | ((c >> 4) & 3);
}

__device__ __forceinline__ void gload_lds16(const void* g, void* l) {
  __builtin_amdgcn_global_load_lds(
      (const __attribute__((address_space(1))) unsigned char*)g,
      (__attribute__((address_space(3))) unsigned char*)l,
      16, 0, 0);
}

// --------------------------- prep kernels ----------------------------------

__global__ void cast_f8(const float* __restrict__ in,
                        unsigned* __restrict__ out, float scale, int n4) {
  int i = blockIdx.x * blockDim.x + threadIdx.x;
  if (i < n4) {
    float4 v = ((const float4*)in)[i];
    out[i] = f8pack4(v.x * scale, v.y * scale, v.z * scale, v.w * scale);
  }
}

// xi f32 [8192,1024] -> xi8 fp8(32*xi) [8192,1024] (sigma on d within 128),
// xit8 fp8(32*xi) [1024,8192] (sigma on p within 128), colsum[1024] fp32.
__global__ void xi_prep8(const float* __restrict__ xi,
                         unsigned char* __restrict__ xi8,
                         unsigned char* __restrict__ xit8,
                         float* __restrict__ colsum) {
  __shared__ float t[32][33];
  __shared__ float cs[8][32];
  int tx = threadIdx.x, ty = threadIdx.y;
  int d0 = blockIdx.x * 32, p0 = blockIdx.y * 32;
  int d = d0 + tx;
  int di = (d & ~127) + sig(d & 127);
  float psum = 0.f;
#pragma unroll
  for (int j = 0; j < 32; j += 8) {
    float v = xi[(long)(p0 + ty + j) * NDIM + d];
    t[ty + j][tx] = v;
    psum += v;
    xi8[(long)(p0 + ty + j) * NDIM + di] = f8b(32.f * v);
  }
  cs[ty][tx] = psum;
  __syncthreads();
  if (ty == 0) {
    float s = 0.f;
#pragma unroll
    for (int k = 0; k < 8; ++k) s += cs[k][tx];
    atomicAdd(&colsum[d0 + tx], s);
  }
  int p = p0 + tx;
  int pi = (p & ~127) + sig(p & 127);
#pragma unroll
  for (int j = 0; j < 32; j += 8)
    xit8[(long)(d0 + ty + j) * NPAT + pi] = f8b(32.f * t[tx][ty + j]);
}

// --------------------------- fp8 GEMM --------------------------------------
// acc[m,n] = sum_k A[m,k]*B[n,k]; A:[M,K] fp8, B:[N,K] fp8, K mult of 128.
// Block tile 128x128, BK=128B, 256 threads (4 waves 2x2; wave tile 64x64).
// LDS row = 128B = 4 pair-chunks of 32B; pair-chunk p of row r stored at
// pair-slot p^(r&3). Lane (q,ln) operand = one aligned 32B load.
// MODE 0: store fp8(acc/32) packed u32   [GEMM1: q]
// MODE 1: F=32*(exp(beta*acc/32)-1); store fp8(F) packed + rowsum atomics
// MODE 2: store f32 (acc/1024 + colsum[col]) / (8192 + rowsum[row]/32)

template <int MODE>
__launch_bounds__(256, 2)
__global__ void gemm_f8(const unsigned char* __restrict__ A,
                        const unsigned char* __restrict__ B,
                        void* __restrict__ Cv, int N, int K,
                        const float* __restrict__ beta_ptr,
                        const float* __restrict__ rowsum,
                        const float* __restrict__ colsum,
                        float* __restrict__ rowsum_out) {
  __shared__ unsigned char smem[32768];
  char* Asm = (char*)smem;
  char* Bsm = (char*)smem + 16384;

  const int tid = threadIdx.x;
  const int wave = tid >> 6;
  const int lane = tid & 63;
  const int wm = wave >> 1, wn = wave & 1;
  const int quad = lane >> 4, ln = lane & 15;

  const long row0 = (long)blockIdx.y * 128;
  const long col0 = (long)blockIdx.x * 128;

  // staging: each gload covers 8 rows x 128B; lane -> row lane>>3, slot lane&7.
  // slot s of row r must hold global 16B chunk (((s>>1)^(r&3))<<1)|(s&1)
  const int r_in = lane >> 3;
  const int csl = lane & 7;
  const int cg = ((((csl >> 1) ^ (r_in & 3)) << 1) | (csl & 1));
  const unsigned char* gA[4];
  const unsigned char* gB[4];
  char* lA[4];
  char* lB[4];
#pragma unroll
  for (int p = 0; p < 4; ++p) {
    int grp = wave * 4 + p;
    gA[p] = A + (row0 + grp * 8 + r_in) * (long)K + cg * 16;
    gB[p] = B + (col0 + grp * 8 + r_in) * (long)K + cg * 16;
    lA[p] = Asm + grp * 1024;
    lB[p] = Bsm + grp * 1024;
  }

  // fragment addressing: row R = base+t*16+ln -> R&3 == ln&3, so the
  // swizzled pair-slot (quad ^ (R&3)) is tile-independent.
  const int ps = (quad ^ (ln & 3)) * 32;
  const int base_a = (wm * 64 + ln) * 128 + ps;
  const int base_b = (wn * 64 + ln) * 128 + ps;

  f32x4 acc[4][4] = {};

  for (int kt = 0; kt < K; kt += 128) {
#pragma unroll
    for (int p = 0; p < 4; ++p) gload_lds16(gA[p], lA[p]);
#pragma unroll
    for (int p = 0; p < 4; ++p) gload_lds16(gB[p], lB[p]);
#pragma unroll
    for (int p = 0; p < 4; ++p) { gA[p] += 128; gB[p] += 128; }
    __syncthreads();

    int8v af[4], bfv[4];
#pragma unroll
    for (int t = 0; t < 4; ++t)
      af[t] = *(const int8v*)(Asm + base_a + t * 2048);
#pragma unroll
    for (int t = 0; t < 4; ++t)
      bfv[t] = *(const int8v*)(Bsm + base_b + t * 2048);
#pragma unroll
    for (int mt = 0; mt < 4; ++mt)
#pragma unroll
      for (int nt = 0; nt < 4; ++nt)
        acc[mt][nt] = __builtin_amdgcn_mfma_scale_f32_16x16x128_f8f6f4(
            af[mt], bfv[nt], acc[mt][nt], 0, 0, 0, 0x7f7f7f7f, 0, 0x7f7f7f7f);
    __syncthreads();
  }

  // epilogue. C/D: col = ln (within 16-tile), row = quad*4 + r.
  if (MODE == 0) {
    unsigned* C32 = (unsigned*)Cv;
    const float s = 1.0f / 32.0f;
#pragma unroll
    for (int mt = 0; mt < 4; ++mt)
#pragma unroll
      for (int r = 0; r < 4; ++r) {
        long row = row0 + wm * 64 + mt * 16 + quad * 4 + r;
        unsigned w = f8pack4(acc[mt][0][r] * s, acc[mt][1][r] * s,
                             acc[mt][2][r] * s, acc[mt][3][r] * s);
        C32[row * (N >> 2) + (col0 >> 2) + wn * 16 + ln] = w;
      }
  } else if (MODE == 1) {
    unsigned* C32 = (unsigned*)Cv;
    const float bs = beta_ptr[0] * (1.0f / 32.0f);
#pragma unroll
    for (int mt = 0; mt < 4; ++mt)
#pragma unroll
      for (int r = 0; r < 4; ++r) {
        long row = row0 + wm * 64 + mt * 16 + quad * 4 + r;
        float e0 = (__expf(bs * acc[mt][0][r]) - 1.0f) * 32.f;
        float e1 = (__expf(bs * acc[mt][1][r]) - 1.0f) * 32.f;
        float e2 = (__expf(bs * acc[mt][2][r]) - 1.0f) * 32.f;
        float e3 = (__expf(bs * acc[mt][3][r]) - 1.0f) * 32.f;
        C32[row * (N >> 2) + (col0 >> 2) + wn * 16 + ln] =
            f8pack4(e0, e1, e2, e3);
        float s = e0 + e1 + e2 + e3;
        s += __shfl_xor(s, 1, 64);
        s += __shfl_xor(s, 2, 64);
        s += __shfl_xor(s, 4, 64);
        s += __shfl_xor(s, 8, 64);
        if (ln == 0) atomicAdd(&rowsum_out[row], s);
      }
  } else {
    float* C = (float*)Cv;
#pragma unroll
    for (int mt = 0; mt < 4; ++mt)
#pragma unroll
      for (int r = 0; r < 4; ++r) {
        long row = row0 + wm * 64 + mt * 16 + quad * 4 + r;
        float inv = 1.0f / (8192.0f + rowsum[row] * (1.0f / 32.0f));
#pragma unroll
        for (int nt = 0; nt < 4; ++nt) {
          long col = col0 + wn * 64 + nt * 16 + ln;
          C[row * N + col] =
              (acc[mt][nt][r] * (1.0f / 1024.0f) + colsum[col]) * inv;
        }
      }
  }
}

// --------------------------- launch ----------------------------------------

extern "C" void kernel_launch(void* const* d_in, const int* in_sizes, int n_in,
                              void* d_out, int out_size, void* d_ws,
                              size_t ws_size, hipStream_t stream) {
  const float* x    = (const float*)d_in[0];
  const float* wq   = (const float*)d_in[1];
  const float* xi   = (const float*)d_in[2];
  const float* beta = (const float*)d_in[3];
  float* out = (float*)d_out;

  char* ws = (char*)d_ws;
  const size_t MB = 1024 * 1024;
  unsigned char* x8   = (unsigned char*)(ws);             //  8 MiB
  unsigned char* wq8  = (unsigned char*)(ws + 8 * MB);    //  1 MiB
  unsigned char* q8   = (unsigned char*)(ws + 9 * MB);    //  8 MiB
  unsigned char* xi8  = (unsigned char*)(ws + 17 * MB);   //  8 MiB
  unsigned char* xit8 = (unsigned char*)(ws + 25 * MB);   //  8 MiB
  float*         rs   = (float*)(ws + 33 * MB);           // 32 KiB
  float*         csum = (float*)(ws + 33 * MB + 32768);   //  4 KiB
  unsigned char* E8   = (unsigned char*)(ws + 34 * MB);   // 64 MiB

  hipMemsetAsync(rs, 0, 36864, stream);  // rs + colsum

  cast_f8<<<(NROW * NDIM / 4) / 256, 256, 0, stream>>>(
      x, (unsigned*)x8, 1.0f, NROW * NDIM / 4);
  cast_f8<<<(NDIM * NDIM / 4) / 256, 256, 0, stream>>>(
      wq, (unsigned*)wq8, 32.0f, NDIM * NDIM / 4);
  xi_prep8<<<dim3(NDIM / 32, NPAT / 32), dim3(32, 8), 0, stream>>>(
      xi, xi8, xit8, csum);

  // GEMM1: q = x @ wq^T (acc = 32q), store fp8(q) packed. 512 blocks.
  gemm_f8<0><<<dim3(NDIM / 128, NROW / 128), 256, 0, stream>>>(
      x8, wq8, q8, NDIM, NDIM, nullptr, nullptr, nullptr, nullptr);

  // GEMM2: F = 32*(exp(beta*q.xi)-1), fp8 packed + rowsums. 4096 blocks.
  gemm_f8<1><<<dim3(NPAT / 128, NROW / 128), 256, 0, stream>>>(
      q8, xi8, E8, NPAT, NDIM, beta, nullptr, nullptr, rs);

  // GEMM3: out = (colsum + F@xi/32) / (8192 + rowsum/32). 512 blocks.
  gemm_f8<2><<<dim3(NDIM / 128, NROW / 128), 256, 0, stream>>>(
      E8, xit8, out, NDIM, NPAT, nullptr, rs, csum, nullptr);
}